// Round 6
// baseline (158.196 us; speedup 1.0000x reference)
//
#include <hip/hip_runtime.h>
#include <hip/hip_bf16.h>

#define NROW 50000
#define DIN 128
#define DM 256
#define HH 4
#define NC 40
#define BHN 200000
#define NBLK 1563   // ceil(50000/32), 32 rows per wave

typedef float f32x4 __attribute__((ext_vector_type(4)));
typedef short bf16x8 __attribute__((ext_vector_type(8)));

__device__ __forceinline__ unsigned short f2bf(float x) {
    unsigned int u = __float_as_uint(x);
    u += 0x7fffu + ((u >> 16) & 1u);
    return (unsigned short)(u >> 16);
}

__device__ __forceinline__ unsigned int pk2(float lo, float hi) {
    __hip_bfloat162 h = __float22bfloat162_rn(make_float2(lo, hi));
    return *(unsigned int*)&h;
}

__device__ __forceinline__ float bf2f(unsigned short s) {
    return __uint_as_float(((unsigned int)s) << 16);
}

// -------- prep: [0,782) scatter | [782,798) Wpk | [798,810) Wgpk | [810,850) bias2+cs --------
// Wpk  [kc][t][ln][8]: fragment-order packed bf16 of Win^T
// Wgpk [h][kc][t][ln][8]: fragment-order packed bf16 of gamma*Wh^T
__global__ __launch_bounds__(256) void k_prep(const int* __restrict__ pi,
                                              const float* __restrict__ pv,
                                              const float* __restrict__ Win,
                                              const float* __restrict__ Wh,
                                              const float* __restrict__ gamma,
                                              const float* __restrict__ beta,
                                              const float* __restrict__ bh,
                                              float* __restrict__ vcol,
                                              unsigned short* __restrict__ Wpk,
                                              unsigned short* __restrict__ Wgpk,
                                              float* __restrict__ bias2,
                                              float* __restrict__ cs) {
    const int bid = blockIdx.x, tid = threadIdx.x;
    if (bid < 782) {
        int k = bid * 256 + tid;
        if (k < BHN) {
            int b = (k >= 150000) ? 3 : (k >= 100000) ? 2 : (k >= 50000) ? 1 : 0;
            int col = pi[2 * BHN + k];
            vcol[b * NROW + col] = pv[k];
        }
    } else if (bid < 798) {
        int base = (bid - 782) * 512;
        #pragma unroll
        for (int q = 0; q < 2; ++q) {
            int s = base + q * 256 + tid;
            int ln = s & 63;
            int t  = (s >> 6) & 15;
            int kc = s >> 10;
            int n  = t * 16 + (ln & 15);
            int kb = kc * 32 + ((ln >> 4) << 3);
            union { unsigned int ui[4]; uint4 v4; } u;
            #pragma unroll
            for (int jj = 0; jj < 4; ++jj)
                u.ui[jj] = pk2(Win[(kb + 2 * jj) * DM + n], Win[(kb + 2 * jj + 1) * DM + n]);
            *(uint4*)&Wpk[s * 8] = u.v4;
        }
    } else if (bid < 810) {
        int base = (bid - 798) * 512;
        #pragma unroll
        for (int q = 0; q < 2; ++q) {
            int s = base + q * 256 + tid;
            int ln = s & 63;
            int u6 = s >> 6;
            int t  = u6 % 3;
            int v6 = u6 / 3;
            int kc = v6 & 7;
            int h  = v6 >> 3;
            int c  = t * 16 + (ln & 15);
            int d0 = h * 256 + kc * 32 + ((ln >> 4) << 3);
            union { unsigned int ui[4]; uint4 v4; } u;
            if (c < NC) {
                #pragma unroll
                for (int jj = 0; jj < 4; ++jj)
                    u.ui[jj] = pk2(gamma[d0 + 2 * jj] * Wh[(d0 + 2 * jj) * NC + c],
                                   gamma[d0 + 2 * jj + 1] * Wh[(d0 + 2 * jj + 1) * NC + c]);
            } else {
                u.v4 = make_uint4(0u, 0u, 0u, 0u);
            }
            *(uint4*)&Wgpk[s * 8] = u.v4;
        }
    } else {   // bias2[c] = bh[c] + sum_d beta[d]*Wh[d][c]; cs[c] = sum_d gamma[d]*Wh[d][c]
        __shared__ float red[256], red2[256];
        int c = bid - 810;
        float sb = 0.f, sc = 0.f;
        #pragma unroll
        for (int q = 0; q < 4; ++q) {
            int d = tid + 256 * q;
            float w = Wh[d * NC + c];
            sb = fmaf(beta[d], w, sb);
            sc = fmaf(gamma[d], w, sc);
        }
        red[tid] = sb; red2[tid] = sc;
        __syncthreads();
        for (int st = 128; st > 0; st >>= 1) {
            if (tid < st) { red[tid] += red[tid + st]; red2[tid] += red2[tid + st]; }
            __syncthreads();
        }
        if (tid == 0) { bias2[c] = bh[c] + red[0]; cs[c] = red2[0]; }
    }
}

// -------- fused: 32 rows/wave, col-halved phase1 (no spill), affine-LN epilogue --------
__global__ __launch_bounds__(64, 2) void k_fused(
    const float* __restrict__ feats, const float* __restrict__ appd,
    const unsigned short* __restrict__ Wpk,
    const unsigned short* __restrict__ Wgpk,
    const float* __restrict__ vcol,
    const float* __restrict__ b_in,
    const float* __restrict__ bias2,
    const float* __restrict__ cs,
    float* __restrict__ out)
{
    __shared__ __align__(16) unsigned short Gb[32 * 264];
    __shared__ float rsS[32], rmS[32];

    const int tid = threadIdx.x;
    const int quad = tid >> 4;
    const int lr = tid & 15;
    const int j0 = blockIdx.x * 32;

    const int ar0 = min(j0 + lr, NROW - 1);
    const int ar1 = min(j0 + 16 + lr, NROW - 1);

    // v at C-layout rows: vhh[rt][h][rg] for rows rt*16+quad*4+rg (live to epilogue)
    float vhh[2][HH][4];
    #pragma unroll
    for (int rt = 0; rt < 2; ++rt)
        #pragma unroll
        for (int h = 0; h < HH; ++h)
            #pragma unroll
            for (int rg = 0; rg < 4; ++rg)
                vhh[rt][h][rg] = vcol[h * NROW + min(j0 + rt * 16 + quad * 4 + rg, NROW - 1)];

    const f32x4 zero4 = {0.f, 0.f, 0.f, 0.f};
    float s_[2][4] = {}, ss_[2][4] = {};

    // ---- phase 1+2 per column half: accG[2][8] (64 regs), stats + G spill to LDS ----
    #pragma unroll
    for (int ch = 0; ch < 2; ++ch) {
        f32x4 accG[2][8];
        #pragma unroll
        for (int rt = 0; rt < 2; ++rt)
            #pragma unroll
            for (int t = 0; t < 8; ++t) accG[rt][t] = zero4;

        #pragma unroll
        for (int kc = 0; kc < 8; ++kc) {
            const float* src = (kc < 4) ? feats : appd;
            const int ko = (kc & 3) * 32 + quad * 8;
            union { unsigned int ui[4]; bf16x8 v; } a0, a1;
            {
                float4 x0 = *(const float4*)&src[(size_t)ar0 * DIN + ko];
                float4 x1 = *(const float4*)&src[(size_t)ar0 * DIN + ko + 4];
                a0.ui[0] = pk2(x0.x, x0.y); a0.ui[1] = pk2(x0.z, x0.w);
                a0.ui[2] = pk2(x1.x, x1.y); a0.ui[3] = pk2(x1.z, x1.w);
                float4 y0 = *(const float4*)&src[(size_t)ar1 * DIN + ko];
                float4 y1 = *(const float4*)&src[(size_t)ar1 * DIN + ko + 4];
                a1.ui[0] = pk2(y0.x, y0.y); a1.ui[1] = pk2(y0.z, y0.w);
                a1.ui[2] = pk2(y1.x, y1.y); a1.ui[3] = pk2(y1.z, y1.w);
            }
            #pragma unroll
            for (int t = 0; t < 8; ++t) {
                bf16x8 bf = *(const bf16x8*)&Wpk[(size_t)(((kc * 16 + ch * 8 + t) << 6) + tid) * 8];
                accG[0][t] = __builtin_amdgcn_mfma_f32_16x16x32_bf16(a0.v, bf, accG[0][t], 0, 0, 0);
                accG[1][t] = __builtin_amdgcn_mfma_f32_16x16x32_bf16(a1.v, bf, accG[1][t], 0, 0, 0);
            }
        }
        // stats partial + spill G
        float bt[8];
        #pragma unroll
        for (int t = 0; t < 8; ++t) bt[t] = b_in[(ch * 8 + t) * 16 + lr];
        #pragma unroll
        for (int rt = 0; rt < 2; ++rt)
            #pragma unroll
            for (int t = 0; t < 8; ++t)
                #pragma unroll
                for (int rg = 0; rg < 4; ++rg) {
                    float gg = accG[rt][t][rg];
                    Gb[(rt * 16 + quad * 4 + rg) * 264 + (ch * 8 + t) * 16 + lr] = f2bf(gg);
                    #pragma unroll
                    for (int h = 0; h < HH; ++h) {
                        float v = vhh[rt][h][rg];
                        float y = v * fmaxf(fmaf(v, gg, bt[t]), 0.f);
                        s_[rt][rg] += y;
                        ss_[rt][rg] = fmaf(y, y, ss_[rt][rg]);
                    }
                }
    }

    // ---- finalize stats ----
    #pragma unroll
    for (int m = 1; m <= 8; m <<= 1)
        #pragma unroll
        for (int rt = 0; rt < 2; ++rt)
            #pragma unroll
            for (int rg = 0; rg < 4; ++rg) {
                s_[rt][rg] += __shfl_xor(s_[rt][rg], m);
                ss_[rt][rg] += __shfl_xor(ss_[rt][rg], m);
            }
    if (lr == 0) {
        #pragma unroll
        for (int rt = 0; rt < 2; ++rt)
            #pragma unroll
            for (int rg = 0; rg < 4; ++rg) {
                float mm = s_[rt][rg] * (1.f / 1024.f);
                float var = ss_[rt][rg] * (1.f / 1024.f) - mm * mm;
                float r_ = rsqrtf(var + 1e-5f);
                rsS[rt * 16 + quad * 4 + rg] = r_;
                rmS[rt * 16 + quad * 4 + rg] = r_ * mm;
            }
    }
    __syncthreads();

    // ---- phase 3: MFMA on yhat = relu(v*g+b); per-head accumulators ----
    float vm[HH][2];
    #pragma unroll
    for (int h = 0; h < HH; ++h) {
        vm[h][0] = vcol[h * NROW + min(j0 + lr, NROW - 1)];
        vm[h][1] = vcol[h * NROW + min(j0 + 16 + lr, NROW - 1)];
    }

    f32x4 accO[HH][2][3];
    #pragma unroll
    for (int h = 0; h < HH; ++h)
        #pragma unroll
        for (int rt = 0; rt < 2; ++rt)
            #pragma unroll
            for (int t = 0; t < 3; ++t) accO[h][rt][t] = zero4;

    #pragma unroll
    for (int kc = 0; kc < 8; ++kc) {
        bf16x8 gf0 = *(const bf16x8*)&Gb[lr * 264 + kc * 32 + quad * 8];
        bf16x8 gf1 = *(const bf16x8*)&Gb[(16 + lr) * 264 + kc * 32 + quad * 8];
        float4 bA = *(const float4*)&b_in[kc * 32 + quad * 8];
        float4 bB = *(const float4*)&b_in[kc * 32 + quad * 8 + 4];
        float bb[8] = {bA.x, bA.y, bA.z, bA.w, bB.x, bB.y, bB.z, bB.w};
        float g0[8], g1[8];
        #pragma unroll
        for (int j = 0; j < 8; ++j) {
            g0[j] = bf2f((unsigned short)gf0[j]);
            g1[j] = bf2f((unsigned short)gf1[j]);
        }
        #pragma unroll
        for (int h = 0; h < HH; ++h) {
            union { unsigned int ui[4]; bf16x8 v; } u0, u1;
            #pragma unroll
            for (int jj = 0; jj < 4; ++jj) {
                float ya = fmaxf(fmaf(vm[h][0], g0[2 * jj], bb[2 * jj]), 0.f);
                float yb = fmaxf(fmaf(vm[h][0], g0[2 * jj + 1], bb[2 * jj + 1]), 0.f);
                u0.ui[jj] = pk2(ya, yb);
                float yc = fmaxf(fmaf(vm[h][1], g1[2 * jj], bb[2 * jj]), 0.f);
                float yd = fmaxf(fmaf(vm[h][1], g1[2 * jj + 1], bb[2 * jj + 1]), 0.f);
                u1.ui[jj] = pk2(yc, yd);
            }
            #pragma unroll
            for (int t = 0; t < 3; ++t) {
                bf16x8 wf = *(const bf16x8*)&Wgpk[(size_t)((((h * 8 + kc) * 3 + t) << 6) + tid) * 8];
                accO[h][0][t] = __builtin_amdgcn_mfma_f32_16x16x32_bf16(u0.v, wf, accO[h][0][t], 0, 0, 0);
                accO[h][1][t] = __builtin_amdgcn_mfma_f32_16x16x32_bf16(u1.v, wf, accO[h][1][t], 0, 0, 0);
            }
        }
    }

    // ---- epilogue: out = rs*(sum_h v_h*accO_h) - rs*mu*cs + bias2 ----
    float ct[3], b2[3];
    #pragma unroll
    for (int t = 0; t < 3; ++t) {
        int c = t * 16 + lr;
        ct[t] = (c < NC) ? cs[c] : 0.f;
        b2[t] = (c < NC) ? bias2[c] : 0.f;
    }
    #pragma unroll
    for (int rt = 0; rt < 2; ++rt)
        #pragma unroll
        for (int rg = 0; rg < 4; ++rg) {
            int rr = rt * 16 + quad * 4 + rg;
            int row = j0 + rr;
            if (row < NROW) {
                float rsv = rsS[rr], rmv = rmS[rr];
                #pragma unroll
                for (int t = 0; t < 3; ++t) {
                    int c = t * 16 + lr;
                    if (c < NC) {
                        float raw = vhh[rt][0][rg] * accO[0][rt][t][rg];
                        raw = fmaf(vhh[rt][1][rg], accO[1][rt][t][rg], raw);
                        raw = fmaf(vhh[rt][2][rg], accO[2][rt][t][rg], raw);
                        raw = fmaf(vhh[rt][3][rg], accO[3][rt][t][rg], raw);
                        float base = fmaf(-rmv, ct[t], b2[t]);
                        out[(size_t)row * NC + c] = fmaf(rsv, raw, base);
                    }
                }
            }
        }
}

extern "C" void kernel_launch(void* const* d_in, const int* in_sizes, int n_in,
                              void* d_out, int out_size, void* d_ws, size_t ws_size,
                              hipStream_t stream) {
    const int*   pi    = (const int*)d_in[0];
    const float* pv    = (const float*)d_in[1];
    const float* feats = (const float*)d_in[2];
    const float* appd  = (const float*)d_in[3];
    const float* Win   = (const float*)d_in[4];
    const float* b_in  = (const float*)d_in[5];
    const float* gamma = (const float*)d_in[6];
    const float* beta  = (const float*)d_in[7];
    const float* Wh    = (const float*)d_in[8];
    const float* bh    = (const float*)d_in[9];
    float* out = (float*)d_out;

    char* w = (char*)d_ws;
    float*          vcolW  = (float*)w;                        // 800000 B
    unsigned short* WpkW   = (unsigned short*)(w + 800000);    // 131072 B
    unsigned short* WgpkW  = (unsigned short*)(w + 931072);    // 98304 B
    float*          bias2W = (float*)(w + 1029376);            // 160 B
    float*          csW    = (float*)(w + 1029536);            // 160 B

    k_prep<<<850, 256, 0, stream>>>(pi, pv, Win, Wh, gamma, beta, bh, vcolW, WpkW, WgpkW, bias2W, csW);
    k_fused<<<NBLK, 64, 0, stream>>>(feats, appd, WpkW, WgpkW, vcolW, b_in, bias2W, csW, out);
}